// Round 10
// baseline (188.113 us; speedup 1.0000x reference)
//
#include <hip/hip_runtime.h>
#include <math.h>

// Problem constants (match reference: B,C,W,H,D = 2,256,32,32,32)
#define Bc   2
#define Cc   256
#define Nn   32768            // W*H*D
#define CHc  128              // C/2
#define LN_EPS 1e-5f

// R15 tiling: R11 structure (2 tiles/block, prefetch-in-place) + NT loads
#define TN    64              // spatial positions per tile
#define ITERS 2               // tiles per block (register-reuse prefetch)
#define TPB   512             // threads per block (8 waves)
#define NQ    16              // n-quads per tile (TN/4)
#define CPG   8               // channels per thread (32 groups x 8 = 256)
#define GRIDX (Nn / (TN * ITERS))   // 256 -> x Bc = 512 blocks (2/CU)
#define NSLOT 32              // atomic-contention slots

// Non-temporal float4 load: data is read EXACTLY once (zero reuse) -> skip
// L2 allocation. R14 proved this alone = fused 45.5 -> ~36us.
typedef float v4f __attribute__((ext_vector_type(4)));
static __device__ __forceinline__ float4 ntload4(const float* p) {
  v4f v = __builtin_nontemporal_load((const v4f*)p);
  return make_float4(v.x, v.y, v.z, v.w);
}

// ---------------------------------------------------------------------------
// R15 gc_fused: NT loads (R14 win, -10us) composed with R11's spill-free
// 2-tile prefetch-in-place (88 VGPR, verified absmax 0.0).
//
// Rationale: NT requests now carry ~900cy HBM-class latency instead of
// ~200cy L2-hit -> exposed load phases cost more, and keeping the next
// tile's 32 loads in flight across phase1+B1+phase2+phase3 is worth more
// than the -2us it was without NT (R11 vs R8).
// Pre-committed: compose -> total ~176-181; null -> revert to R14 + declare
// pattern roofline; regression -> 512-block grid undersubscribes, revert.
// UNSHIFTED softmax (shift-invariant; |mask| <~ 2, fp32-exact).
// ---------------------------------------------------------------------------
__global__ __launch_bounds__(TPB, 2) void gc_fused(
    const float* __restrict__ S, const float* __restrict__ T,
    const float* __restrict__ wms, const float* __restrict__ bms,
    const float* __restrict__ wmt, const float* __restrict__ bmt,
    float* __restrict__ ctxnum,   // [NSLOT][2][Bc][Cc] raw weighted sums
    float* __restrict__ rowsum,   // [NSLOT][Bc][Cc]
    float* __restrict__ den,      // [NSLOT][4] softmax denominators
    float* __restrict__ sumsq) {  // [NSLOT]
  const int b    = blockIdx.y;
  const int tid  = threadIdx.x;
  const int nq   = tid & (NQ - 1);
  const int cg   = tid >> 4;           // 0..31
  const int wv   = tid >> 6;
  const int lane = tid & 63;
  const int c0   = cg * CPG;
  const int slot = blockIdx.x & (NSLOT - 1);
  const int nbase = blockIdx.x * (ITERS * TN) + nq * 4;

  __shared__ float4 mredw[2][8][NQ];   // 4 KB   wave-level mask partials
  __shared__ float  creds[Cc * 17];    // 17 KB  ctx_s partials
  __shared__ float  credt[Cc * 17];    // 17 KB  ctx_t partials
  __shared__ float  credd[Cc * 17];    // 17 KB  rowsum partials
  __shared__ float  sqred[8];

  const float bS = bms[0];
  const float bT = bmt[0];

  const float* Sp = S + ((size_t)b * Cc + c0) * Nn + nbase;
  const float* Tp = T + ((size_t)b * Cc + c0) * Nn + nbase;

  float wS[CPG], wT[CPG];
#pragma unroll
  for (int i = 0; i < CPG; ++i) { wS[i] = wms[c0 + i]; wT[i] = wmt[c0 + i]; }

  // running accumulators across the tiles
  float accS = 0.f, accT = 0.f, accR = 0.f;
  float dens = 0.f, dent = 0.f, sq = 0.f;

  // ---- prologue: tile 0 loads (16 independent NT float4) ----
  float4 s4[CPG], t4[CPG];
#pragma unroll
  for (int i = 0; i < CPG; ++i) s4[i] = ntload4(Sp + (size_t)i * Nn);
#pragma unroll
  for (int i = 0; i < CPG; ++i) t4[i] = ntload4(Tp + (size_t)i * Nn);

  for (int it = 0; it < ITERS; ++it) {
    // ---- phase 1: mask partials (register + shfl) ----
    float4 ms = make_float4(0.f, 0.f, 0.f, 0.f);
    float4 mt = make_float4(0.f, 0.f, 0.f, 0.f);
#pragma unroll
    for (int i = 0; i < CPG; ++i) {
      ms.x += wS[i] * s4[i].x; ms.y += wS[i] * s4[i].y;
      ms.z += wS[i] * s4[i].z; ms.w += wS[i] * s4[i].w;
      mt.x += wT[i] * t4[i].x; mt.y += wT[i] * t4[i].y;
      mt.z += wT[i] * t4[i].z; mt.w += wT[i] * t4[i].w;
    }
#pragma unroll
    for (int m = 16; m <= 32; m <<= 1) {
      ms.x += __shfl_xor(ms.x, m); ms.y += __shfl_xor(ms.y, m);
      ms.z += __shfl_xor(ms.z, m); ms.w += __shfl_xor(ms.w, m);
      mt.x += __shfl_xor(mt.x, m); mt.y += __shfl_xor(mt.y, m);
      mt.z += __shfl_xor(mt.z, m); mt.w += __shfl_xor(mt.w, m);
    }
    if (lane < NQ) { mredw[0][wv][nq] = ms; mredw[1][wv][nq] = mt; }

    __syncthreads();   // B1: mredw(it) visible; guards cred*(it-1) reads
                       // from this iteration's phase-3 writes.

    // ---- phase 2: assemble mask, exponentiate ----
    float4 Ms = make_float4(0.f, 0.f, 0.f, 0.f);
    float4 Mt = make_float4(0.f, 0.f, 0.f, 0.f);
#pragma unroll
    for (int w = 0; w < 8; ++w) {
      const float4 a = mredw[0][w][nq];
      Ms.x += a.x; Ms.y += a.y; Ms.z += a.z; Ms.w += a.w;
      const float4 c = mredw[1][w][nq];
      Mt.x += c.x; Mt.y += c.y; Mt.z += c.z; Mt.w += c.w;
    }
    float4 es, et;
    es.x = __expf(Ms.x + bS); es.y = __expf(Ms.y + bS);
    es.z = __expf(Ms.z + bS); es.w = __expf(Ms.w + bS);
    et.x = __expf(Mt.x + bT); et.y = __expf(Mt.y + bT);
    et.z = __expf(Mt.z + bT); et.w = __expf(Mt.w + bT);
    dens += es.x + es.y + es.z + es.w;
    dent += et.x + et.y + et.z + et.w;

    // ---- phase 3: write all three partial sets; prefetch next tile into
    // the SAME registers exactly where s4[i]/t4[i] die (NT) ----
    const int nextoff = (it + 1) * TN;
    const bool hasnext = (it + 1 < ITERS);
#pragma unroll
    for (int i = 0; i < CPG; ++i) {
      creds[(c0 + i) * 17 + nq] =
          s4[i].x * es.x + s4[i].y * es.y + s4[i].z * es.z + s4[i].w * es.w;
      credt[(c0 + i) * 17 + nq] =
          t4[i].x * et.x + t4[i].y * et.y + t4[i].z * et.z + t4[i].w * et.w;
      const float dx = s4[i].x - t4[i].x, dy = s4[i].y - t4[i].y;
      const float dz = s4[i].z - t4[i].z, dw = s4[i].w - t4[i].w;
      credd[(c0 + i) * 17 + nq] = dx + dy + dz + dw;
      sq += dx * dx + dy * dy + dz * dz + dw * dw;
      if (hasnext) {   // s4[i]/t4[i] dead here -> reuse, no spill
        s4[i] = ntload4(Sp + (size_t)i * Nn + nextoff);
        t4[i] = ntload4(Tp + (size_t)i * Nn + nextoff);
      }
    }

    __syncthreads();   // B2: cred*(it) visible; loads stay in flight

    // ---- phase 4: LDS-only accumulate (covers the prefetch latency) ----
    if (tid < Cc) {
      float a = 0.f, r = 0.f;
#pragma unroll
      for (int k = 0; k < NQ; ++k) {
        a += creds[tid * 17 + k];
        r += credd[tid * 17 + k];
      }
      accS += a; accR += r;
    } else {
      float t = 0.f;
#pragma unroll
      for (int k = 0; k < NQ; ++k) t += credt[(tid - Cc) * 17 + k];
      accT += t;
    }
  }

  // ---- epilogue: one atomic phase per block ----
#pragma unroll
  for (int m = 1; m < 64; m <<= 1) sq += __shfl_xor(sq, m);
  if (lane == 0) sqred[wv] = sq;
  // dens/dent identical across the 4 cg-subgroups; sum the 16 nq lanes
#pragma unroll
  for (int m = 1; m <= 8; m <<= 1) {
    dens += __shfl_xor(dens, m);
    dent += __shfl_xor(dent, m);
  }
  __syncthreads();   // sqred visible

  if (tid < Cc) {
    atomicAdd(&ctxnum[(((size_t)slot * 2 + 0) * Bc + b) * Cc + tid], accS);
    atomicAdd(&rowsum[((size_t)slot * Bc + b) * Cc + tid], accR);
  } else {
    atomicAdd(&ctxnum[(((size_t)slot * 2 + 1) * Bc + b) * Cc + (tid - Cc)],
              accT);
  }
  if (tid == 0) {
    atomicAdd(&den[slot * 4 + 0 * Bc + b], dens);
    atomicAdd(&den[slot * 4 + 1 * Bc + b], dent);
    float v = 0.f;
#pragma unroll
    for (int w = 0; w < 8; ++w) v += sqred[w];
    atomicAdd(&sumsq[slot], v);
  }
}

// ---------------------------------------------------------------------------
// K4a: channel_add MLP per (tt,b). grid 4, block 1024. ctx = fold NSLOT
// slots at load time. w2 row preloaded early (fetch hides under stages 1-2).
// ---------------------------------------------------------------------------
__global__ __launch_bounds__(1024) void gc_k4a_mlp(
    const float* __restrict__ ctxr, const float* __restrict__ den,
    const float* __restrict__ w1s, const float* __restrict__ b1s,
    const float* __restrict__ gs,  const float* __restrict__ bes,
    const float* __restrict__ w2s, const float* __restrict__ b2s,
    const float* __restrict__ w1t, const float* __restrict__ b1t,
    const float* __restrict__ gt,  const float* __restrict__ bet,
    const float* __restrict__ w2t, const float* __restrict__ b2t,
    float* __restrict__ addv) {
  const int tt  = blockIdx.x >> 1;
  const int b   = blockIdx.x & 1;
  const int tid = threadIdx.x;

  const float* w1 = tt ? w1t : w1s;
  const float* b1 = tt ? b1t : b1s;
  const float* g  = tt ? gt  : gs;
  const float* be = tt ? bet : bes;
  const float* w2 = tt ? w2t : w2s;
  const float* b2 = tt ? b2t : b2s;

  __shared__ float cxs[Cc];
  __shared__ float part[1024];
  __shared__ float hbuf[CHc];
  __shared__ float hr[CHc];
  __shared__ float2 red2[128];
  __shared__ float mu_s, rstd_s;

  // ---- preload stage-3 weights early (consumed after LN) ----
  const int c3 = tid >> 2, q3 = tid & 3;
  const float* wr3 = w2 + c3 * CHc + q3 * 32;
  float4 w2r[8];
#pragma unroll
  for (int kk = 0; kk < 8; ++kk) w2r[kk] = *(const float4*)(wr3 + kk * 4);

  if (tid < Cc) {
    float num = 0.f, dn = 0.f;
#pragma unroll
    for (int kk = 0; kk < NSLOT; ++kk) {
      num += ctxr[(((size_t)kk * 2 + tt) * Bc + b) * Cc + tid];
      dn  += den[kk * 4 + tt * Bc + b];
    }
    cxs[tid] = num / dn;
  }
  __syncthreads();

  // stage 1: h[j] = sum_c ctx[c]*w1[j][c] + b1[j]   (128 j x 8 segments)
  {
    const int j = tid >> 3, s = tid & 7;
    const float* wr = w1 + j * Cc + s * 32;
    const float4* cx4 = (const float4*)(cxs + s * 32);
    float acc = 0.f;
#pragma unroll
    for (int kk = 0; kk < 8; ++kk) {
      const float4 w = *(const float4*)(wr + kk * 4);
      const float4 x = cx4[kk];
      acc += w.x * x.x + w.y * x.y + w.z * x.z + w.w * x.w;
    }
    part[tid] = acc;
  }
  __syncthreads();
  if (tid < CHc) {
    float h = b1[tid];
#pragma unroll
    for (int q = 0; q < 8; ++q) h += part[tid * 8 + q];
    hbuf[tid] = h;
  }
  __syncthreads();

  // LN stats over 128
  if (tid < CHc) {
    const float v = hbuf[tid];
    red2[tid] = make_float2(v, v * v);
  }
  __syncthreads();
  for (int s = 64; s > 0; s >>= 1) {
    if (tid < s) {
      red2[tid].x += red2[tid + s].x;
      red2[tid].y += red2[tid + s].y;
    }
    __syncthreads();
  }
  if (tid == 0) {
    const float mu = red2[0].x / (float)CHc;
    const float var = red2[0].y / (float)CHc - mu * mu;
    mu_s = mu;
    rstd_s = rsqrtf(var + LN_EPS);
  }
  __syncthreads();
  if (tid < CHc) {
    const float v = (hbuf[tid] - mu_s) * rstd_s * g[tid] + be[tid];
    hr[tid] = v > 0.f ? v : 0.f;
  }
  __syncthreads();

  // stage 3: addv[c] = sum_j hr[j]*w2[c][j] + b2[c]   (256 c x 4 segments)
  {
    const float4* h4 = (const float4*)(hr + q3 * 32);
    float acc = 0.f;
#pragma unroll
    for (int kk = 0; kk < 8; ++kk) {
      const float4 w = w2r[kk];
      const float4 x = h4[kk];
      acc += w.x * x.x + w.y * x.y + w.z * x.z + w.w * x.w;
    }
    part[tid] = acc;
  }
  __syncthreads();
  if (tid < Cc) {
    float acc = b2[tid];
#pragma unroll
    for (int q = 0; q < 4; ++q) acc += part[tid * 4 + q];
    addv[((size_t)tt * Bc + b) * Cc + tid] = acc;
  }
}

// ---------------------------------------------------------------------------
// K4b: final scalar. 1 block, 256 thr. Folds the NSLOT rowsum/sumsq slots.
// out = (sumsq + sum_{b,c} [2*delta*rowsum + N*delta^2]) / B
// ---------------------------------------------------------------------------
__global__ __launch_bounds__(256) void gc_k4b_final(
    const float* __restrict__ addv, const float* __restrict__ rowsum,
    const float* __restrict__ sumsq, float* __restrict__ out) {
  const int tid = threadIdx.x;
  __shared__ float red[256];
  float part = 0.f;
  for (int job = tid; job < Bc * Cc; job += 256) {
    const int c = job & (Cc - 1);
    const int b = job >> 8;
    const float delta = addv[((size_t)0 * Bc + b) * Cc + c] -
                        addv[((size_t)1 * Bc + b) * Cc + c];
    float rs = 0.f;
#pragma unroll
    for (int k = 0; k < NSLOT; ++k)
      rs += rowsum[((size_t)k * Bc + b) * Cc + c];
    part += 2.f * delta * rs + (float)Nn * delta * delta;
  }
  red[tid] = part;
  __syncthreads();
  for (int s = 128; s > 0; s >>= 1) {
    if (tid < s) red[tid] += red[tid + s];
    __syncthreads();
  }
  if (tid == 0) {
    float sq = 0.f;
#pragma unroll
    for (int k = 0; k < NSLOT; ++k) sq += sumsq[k];
    out[0] = (red[0] + sq) / (float)Bc;
  }
}

// ---------------------------------------------------------------------------
extern "C" void kernel_launch(void* const* d_in, const int* in_sizes, int n_in,
                              void* d_out, int out_size, void* d_ws,
                              size_t ws_size, hipStream_t stream) {
  const float* S   = (const float*)d_in[0];
  const float* T   = (const float*)d_in[1];
  const float* wms = (const float*)d_in[2];
  const float* bms = (const float*)d_in[3];
  const float* wmt = (const float*)d_in[4];
  const float* bmt = (const float*)d_in[5];
  const float* w1s = (const float*)d_in[6];
  const float* b1s = (const float*)d_in[7];
  const float* gs  = (const float*)d_in[8];
  const float* bes = (const float*)d_in[9];
  const float* w2s = (const float*)d_in[10];
  const float* b2s = (const float*)d_in[11];
  const float* w1t = (const float*)d_in[12];
  const float* b1t = (const float*)d_in[13];
  const float* gt  = (const float*)d_in[14];
  const float* bet = (const float*)d_in[15];
  const float* w2t = (const float*)d_in[16];
  const float* b2t = (const float*)d_in[17];
  float* out = (float*)d_out;

  // ws layout (floats) — slotted accumulators first; one memset zeroes all.
  float* ws     = (float*)d_ws;
  float* ctxnum = ws;                               // NSLOT*2*B*C = 32768
  float* rowsum = ctxnum + NSLOT * 2 * Bc * Cc;     // NSLOT*B*C   = 16384
  float* den    = rowsum + NSLOT * Bc * Cc;         // NSLOT*4     = 128
  float* sumsq  = den + NSLOT * 4;                  // NSLOT       = 32
  float* addv   = sumsq + NSLOT;                    // 2*B*C       = 1024

  hipMemsetAsync(d_ws, 0,
                 (NSLOT * (2 * Bc * Cc + Bc * Cc + 4 + 1)) * sizeof(float),
                 stream);

  gc_fused<<<dim3(GRIDX, Bc), TPB, 0, stream>>>(S, T, wms, bms, wmt, bmt,
                                                ctxnum, rowsum, den, sumsq);
  gc_k4a_mlp<<<4, 1024, 0, stream>>>(ctxnum, den, w1s, b1s, gs, bes, w2s, b2s,
                                     w1t, b1t, gt, bet, w2t, b2t, addv);
  gc_k4b_final<<<1, 256, 0, stream>>>(addv, rowsum, sumsq, out);
}